// Round 8
// baseline (74.432 us; speedup 1.0000x reference)
//
#include <hip/hip_runtime.h>
#include <math.h>

#define BB 32
#define CC 768
#define HID 96
#define NPIX 1024
#define KSEL 256
#define BN_EPS_F 1e-5f

typedef __bf16 bf16x8 __attribute__((ext_vector_type(8)));
typedef float f32x4 __attribute__((ext_vector_type(4)));

__device__ __forceinline__ unsigned short f2bf(float f) {
    unsigned u = __float_as_uint(f);
    return (unsigned short)((u + 0x7FFFu + ((u >> 16) & 1u)) >> 16);  // RNE
}
__device__ __forceinline__ unsigned pack2(float lo, float hi) {
    return (unsigned)f2bf(lo) | ((unsigned)f2bf(hi) << 16);
}

// ---------------------------------------------------------------------------
// K1 v5: bf16 MFMA GEMM H[o,n] = sum_c w1[o,c]*x[b,c,n], fused BN+ReLU and
// fused w1 f32->bf16 conversion (k0 eliminated).
// grid (16 n-tiles of 64, 32 b) = 512 blocks, 512 thr = 8 waves (2 blk/CU,
// 4 waves/SIMD). Wave (wo,wn): 48o x 16n, acc = 3 f32x4.
// X path is BARRIER-FREE: B-fragments loaded per-lane direct from global
// (8 dwords, 16-lane groups coalesce to 64B), 4-deep register pipeline,
// f32->bf16 pack in-reg. W staged once per K-half (74.5 KB LDS, stride 388
// shorts == 2 mod 32 dwords -> uniform banks on b128 reads). 3 barriers total.
// ---------------------------------------------------------------------------
__global__ __launch_bounds__(512, 4) void k1_gemm_mfma(
    const float* __restrict__ x, const float* __restrict__ w1,
    const float* __restrict__ gamma, const float* __restrict__ beta,
    const float* __restrict__ mean, const float* __restrict__ var,
    float* __restrict__ h_out)
{
    constexpr int WSTR = 388;                     // shorts per W row
    __shared__ unsigned short Ws[96 * WSTR];      // 74.5 KB, one K-half
    __shared__ float sc_s[HID], sh_s[HID];

    const int t = threadIdx.x;
    const int b = blockIdx.y;
    const int n0 = blockIdx.x * 64;
    const int wave = t >> 6, lane = t & 63;
    const int lm = lane & 15, g = lane >> 4;
    const int wo = wave & 1, wn = wave >> 1;      // 2 wo x 4 wn
    const int n = n0 + wn * 16 + lm;

    if (t < HID) {
        float sc = gamma[t] * rsqrtf(var[t] + BN_EPS_F);
        sc_s[t] = sc;
        sh_s[t] = beta[t] - mean[t] * sc;
    }

    f32x4 acc[3];
#pragma unroll
    for (int mt = 0; mt < 3; ++mt) acc[mt] = (f32x4){0.f, 0.f, 0.f, 0.f};

    // lane's fixed column + its g-subgroup row base
    const float* xcol = x + (size_t)b * CC * NPIX + (size_t)(g * 8) * NPIX + n;

#define STAGE_W(half) do {                                                    \
    _Pragma("unroll")                                                         \
    for (int i = 0; i < 9; ++i) {                                             \
        int idx = t + i * 512;                     /* 0..4607 */              \
        int row = idx / 48, k8 = (idx % 48) * 8;                              \
        const float* src = w1 + (size_t)row * CC + (half) * 384 + k8;         \
        float4 f0 = *reinterpret_cast<const float4*>(src);                    \
        float4 f1 = *reinterpret_cast<const float4*>(src + 4);                \
        uint4 o;                                                              \
        o.x = pack2(f0.x, f0.y); o.y = pack2(f0.z, f0.w);                     \
        o.z = pack2(f1.x, f1.y); o.w = pack2(f1.z, f1.w);                     \
        *reinterpret_cast<uint4*>(&Ws[row * WSTR + k8]) = o;                  \
    } } while (0)

#define LOADX(dst, ck) do {                                                   \
    const float* _p = xcol + (size_t)(ck) * 32 * NPIX;                        \
    _Pragma("unroll")                                                         \
    for (int j = 0; j < 8; ++j) dst[j] = _p[(size_t)j * NPIX];                \
    } while (0)

#define PACKX(bu, src) do {                                                   \
    bu.x = pack2(src[0], src[1]); bu.y = pack2(src[2], src[3]);               \
    bu.z = pack2(src[4], src[5]); bu.w = pack2(src[6], src[7]); } while (0)

#define CHUNK(ckk, bu) do {                                                   \
    bf16x8 bfr = __builtin_bit_cast(bf16x8, bu);                              \
    _Pragma("unroll")                                                         \
    for (int mt = 0; mt < 3; ++mt) {                                          \
        uint4 au = *reinterpret_cast<const uint4*>(                           \
            &Ws[(wo * 48 + mt * 16 + lm) * WSTR + (ckk) * 32 + g * 8]);       \
        acc[mt] = __builtin_amdgcn_mfma_f32_16x16x32_bf16(                    \
            __builtin_bit_cast(bf16x8, au), bfr, acc[mt], 0, 0, 0);           \
    } } while (0)

    float xA[8], xB[8], xC[8], xD[8];

    STAGE_W(0);
    LOADX(xA, 0); LOADX(xB, 1); LOADX(xC, 2); LOADX(xD, 3);
    __syncthreads();

#pragma unroll
    for (int ck = 0; ck < 24; ck += 4) {
        if (ck == 12) {           // K-half boundary: restage W (2 barriers)
            __syncthreads();
            STAGE_W(1);
            __syncthreads();
        }
        uint4 bu0; PACKX(bu0, xA);
        if (ck + 4 < 24) LOADX(xA, ck + 4);
        CHUNK((ck + 0) % 12, bu0);

        uint4 bu1; PACKX(bu1, xB);
        if (ck + 5 < 24) LOADX(xB, ck + 5);
        CHUNK((ck + 1) % 12, bu1);

        uint4 bu2; PACKX(bu2, xC);
        if (ck + 6 < 24) LOADX(xC, ck + 6);
        CHUNK((ck + 2) % 12, bu2);

        uint4 bu3; PACKX(bu3, xD);
        if (ck + 7 < 24) LOADX(xD, ck + 7);
        CHUNK((ck + 3) % 12, bu3);
    }

    // epilogue: C/D col = lm (n), row = g*4 + r (o); BN + ReLU
#pragma unroll
    for (int mt = 0; mt < 3; ++mt) {
#pragma unroll
        for (int r = 0; r < 4; ++r) {
            int o = wo * 48 + mt * 16 + g * 4 + r;
            float v = fmaxf(acc[mt][r] * sc_s[o] + sh_s[o], 0.f);
            h_out[((size_t)b * HID + o) * NPIX + n] = v;
        }
    }
#undef STAGE_W
#undef LOADX
#undef PACKX
#undef CHUNK
}

// ---------------------------------------------------------------------------
// K2: 3x3 conv HID->1, SAME. grid (8 y-tiles of 4 rows, 32 b) = 256 blocks,
// 128 thr (1 px/thread). 16-channel LDS chunks with row halo.
// ---------------------------------------------------------------------------
__global__ __launch_bounds__(128) void k2_conv3x3(
    const float* __restrict__ h_in, const float* __restrict__ w2,
    const float* __restrict__ b2, float* __restrict__ score_out)
{
    __shared__ float hs[16][6][40];   // interior cols 4..35; halo cols 3 and 36
    __shared__ float w2s[HID * 9];

    const int t = threadIdx.x;
    const int ytile = blockIdx.x, b = blockIdx.y;
    const int y = t >> 5, xx = t & 31;
    const int Y = ytile * 4 + y;

    for (int i = t; i < HID * 9; i += 128) w2s[i] = w2[i];

    const float* hb = h_in + (size_t)b * HID * NPIX;
    float acc = 0.f;

    for (int c0 = 0; c0 < HID; c0 += 16) {
        __syncthreads();
        for (int i = t; i < 192; i += 128) {  // zero halo cols (3 and 36)
            int ch = i / 12, rr = (i % 12) >> 1, col = (i & 1) ? 36 : 3;
            hs[ch][rr][col] = 0.f;
        }
#pragma unroll
        for (int i = 0; i < 6; ++i) {
            int idx = t + i * 128;               // 0..767 float4 slots
            int ch = idx / 48, rem = idx % 48;
            int rr = rem >> 3, qq = rem & 7;
            int gy = ytile * 4 - 1 + rr;
            float4 v = (gy >= 0 && gy < 32)
                ? *reinterpret_cast<const float4*>(
                      hb + (size_t)(c0 + ch) * NPIX + gy * 32 + qq * 4)
                : (float4){0.f, 0.f, 0.f, 0.f};
            *reinterpret_cast<float4*>(&hs[ch][rr][4 + qq * 4]) = v;
        }
        __syncthreads();
#pragma unroll
        for (int ch = 0; ch < 16; ++ch) {
            float s = 0.f;
#pragma unroll
            for (int ky = 0; ky < 3; ++ky)
#pragma unroll
                for (int kx = 0; kx < 3; ++kx)
                    s += hs[ch][y + ky][3 + xx + kx] * w2s[(c0 + ch) * 9 + ky * 3 + kx];
            acc += s;
        }
    }
    score_out[b * NPIX + Y * 32 + xx] = acc + b2[0];
}

// ---------------------------------------------------------------------------
// K3: exact top-256 (radix select, first-index tie-break) + softmax ->
// dense weight[1024]. grid 32, 256 thr; elements register-resident (4/thr).
// ---------------------------------------------------------------------------
__global__ __launch_bounds__(256) void k3_topk_softmax(
    const float* __restrict__ score, float* __restrict__ weight)
{
    __shared__ unsigned hist[256];
    __shared__ unsigned wtot[4];
    __shared__ unsigned pcnt16[16];
    __shared__ float redf[4];
    __shared__ unsigned sh_bin, sh_rem;

    const int t = threadIdx.x, b = blockIdx.x;
    const int lane = t & 63, wv = t >> 6;

    float fvals[4];
    unsigned uvals[4];
#pragma unroll
    for (int i = 0; i < 4; ++i) {
        float f = score[b * NPIX + t + 256 * i];
        fvals[i] = f;
        unsigned u = __float_as_uint(f);
        uvals[i] = (u & 0x80000000u) ? ~u : (u | 0x80000000u);
    }

    unsigned prefix = 0, rem = KSEL;
    for (int p = 3; p >= 0; --p) {
        hist[t] = 0;
        __syncthreads();
        const int sh_hi = (p + 1) * 8;
#pragma unroll
        for (int i = 0; i < 4; ++i) {
            unsigned u = uvals[i];
            bool match = (p == 3) || ((u >> sh_hi) == (prefix >> sh_hi));
            if (match) atomicAdd(&hist[(u >> (p * 8)) & 0xffu], 1u);
        }
        __syncthreads();
        unsigned own = hist[t];
        unsigned val = own;
#pragma unroll
        for (int off = 1; off <= 32; off <<= 1) {
            unsigned o2 = __shfl_down(val, off);
            if (lane + off < 64) val += o2;
        }
        if (lane == 0) wtot[wv] = val;
        __syncthreads();
        unsigned suff = val;
        for (int w = wv + 1; w < 4; ++w) suff += wtot[w];
        unsigned nexts = suff - own;        // count with bin > t
        if (suff >= rem && nexts < rem) { sh_bin = (unsigned)t; sh_rem = rem - nexts; }
        __syncthreads();
        prefix |= (sh_bin << (p * 8));
        rem = sh_rem;
        __syncthreads();
    }
    const unsigned T = prefix, need = rem;

    float m = -INFINITY;
#pragma unroll
    for (int i = 0; i < 4; ++i) m = fmaxf(m, fvals[i]);
#pragma unroll
    for (int off = 32; off >= 1; off >>= 1) m = fmaxf(m, __shfl_xor(m, off));
    if (lane == 0) redf[wv] = m;
    __syncthreads();
    m = fmaxf(fmaxf(redf[0], redf[1]), fmaxf(redf[2], redf[3]));

    unsigned lp[4]; bool eqf[4], gtf[4];
    unsigned long long lmask = (1ULL << lane) - 1ULL;
#pragma unroll
    for (int i = 0; i < 4; ++i) {
        bool eq = (uvals[i] == T);
        eqf[i] = eq; gtf[i] = (uvals[i] > T);
        unsigned long long mk = __ballot(eq);
        lp[i] = (unsigned)__popcll(mk & lmask);
        if (lane == 0) pcnt16[i * 4 + wv] = (unsigned)__popcll(mk);
    }
    __syncthreads();
    unsigned cum = 0, baseArr[4];
#pragma unroll
    for (int ii = 0; ii < 4; ++ii) {
        unsigned b0 = cum;
        for (int w = 0; w < wv; ++w) b0 += pcnt16[ii * 4 + w];
        baseArr[ii] = b0;
        for (int w = 0; w < 4; ++w) cum += pcnt16[ii * 4 + w];
    }
    float evals[4], sumExp = 0.f;
#pragma unroll
    for (int i = 0; i < 4; ++i) {
        bool sel = gtf[i] || (eqf[i] && (baseArr[i] + lp[i]) < need);
        float e = sel ? expf(fvals[i] - m) : 0.f;
        evals[i] = e;
        sumExp += e;
    }
#pragma unroll
    for (int off = 32; off >= 1; off >>= 1) sumExp += __shfl_xor(sumExp, off);
    if (lane == 0) redf[wv] = sumExp;
    __syncthreads();
    float inv = 1.0f / (redf[0] + redf[1] + redf[2] + redf[3]);
#pragma unroll
    for (int i = 0; i < 4; ++i)
        weight[b * NPIX + i * 256 + t] = evals[i] * inv;
}

// ---------------------------------------------------------------------------
// K4: v[b,c] = sum_n x[b,c,n]*weight[b,n]. grid 32*192, 4 waves, 1 c/wave.
// ---------------------------------------------------------------------------
__global__ __launch_bounds__(256) void k4_weighted_sum(
    const float* __restrict__ x, const float* __restrict__ weight,
    float* __restrict__ v)
{
    __shared__ float wsm[NPIX];
    const int t = threadIdx.x;
    const int b = blockIdx.x / 192, cg = blockIdx.x % 192;

    *reinterpret_cast<float4*>(&wsm[t * 4]) =
        *reinterpret_cast<const float4*>(&weight[b * NPIX + t * 4]);
    __syncthreads();

    const int lane = t & 63, wvv = t >> 6;
    const int c = cg * 4 + wvv;
    const float* xr = x + ((size_t)b * CC + c) * NPIX;

    float acc = 0.f;
#pragma unroll
    for (int j = 0; j < 4; ++j) {
        int off = j * 256 + lane * 4;
        float4 xv = *reinterpret_cast<const float4*>(xr + off);
        float4 wv4 = *reinterpret_cast<const float4*>(&wsm[off]);
        acc += xv.x * wv4.x + xv.y * wv4.y + xv.z * wv4.z + xv.w * wv4.w;
    }
#pragma unroll
    for (int off = 32; off >= 1; off >>= 1) acc += __shfl_xor(acc, off);
    if (lane == 0) v[(size_t)b * CC + c] = acc;
}

// ---------------------------------------------------------------------------
extern "C" void kernel_launch(void* const* d_in, const int* in_sizes, int n_in,
                              void* d_out, int out_size, void* d_ws, size_t ws_size,
                              hipStream_t stream)
{
    const float* x     = (const float*)d_in[0];
    const float* w1    = (const float*)d_in[1];
    const float* gamma = (const float*)d_in[2];
    const float* beta  = (const float*)d_in[3];
    const float* mean  = (const float*)d_in[4];
    const float* var   = (const float*)d_in[5];
    const float* w2    = (const float*)d_in[6];
    const float* b2    = (const float*)d_in[7];

    float* out   = (float*)d_out;
    float* vout  = out;                  // [32,768]
    float* score = out + BB * CC;        // [32,1024]

    float* h      = (float*)d_ws;                    // 32*96*1024 f32
    float* weight = h + (size_t)BB * HID * NPIX;     // 32*1024 f32

    k1_gemm_mfma<<<dim3(16, BB), 512, 0, stream>>>(x, w1, gamma, beta, mean, var, h);
    k2_conv3x3<<<dim3(8, BB), 128, 0, stream>>>(h, w2, b2, score);
    k3_topk_softmax<<<BB, 256, 0, stream>>>(score, weight);
    k4_weighted_sum<<<BB * (CC / 4), 256, 0, stream>>>(x, weight, vout);
}